// Round 10
// baseline (1653.979 us; speedup 1.0000x reference)
//
#include <hip/hip_runtime.h>
#include <math.h>

// GaussianMixtureLayer: EM loop (<=8 iters, device-side convergence flag) +
// final update + Gaussian log-prob loss. Heavy GEMMs on bf16 MFMA (hi/lo
// 3-term split), operands in FRAGMENT ORDER (wave-contiguous dwordx4 loads).
//   k_quad   : Y = X Linv^T, w = ||y - t||^2 (+ fused num/sw or final loss)
//   k_scatter: S_k = (w.X)^T X   (NCHUNK=2048: 8MB atomic flush vs 16MB)
//   k_fused  : update + Cholesky + two-level trinv IN ONE KERNEL. C and L
//              live entirely in LDS — rounds 5-9 showed the chol-class
//              kernels pinned at ~80-90us by the C/LT global round-trips
//              (2.8MB at 32GB/s latency-bound = the whole dispatch), not by
//              VALU/LDS work. Fusion deletes ~4MB/iter of traffic + 2 launches.

#define NS 16384
#define DD 128
#define KC 16
#define JITTER_ 1e-6f
#define EPS2_ 1e-6f            // (1e-3)^2 Frobenius convergence check
#define LOG_2PI_ 1.8378770664093454f
#define NCHUNK 2048            // scatter samples per block

typedef __attribute__((ext_vector_type(8))) short bf16x8;
typedef __attribute__((ext_vector_type(16))) float f32x16;

// workspace float offsets
enum : int {
  OFF_CUR_M  = 0,            // 16*128
  OFF_CS     = 2048,         // 16*128*128  S accumulator (zeroed by k_fused)
  OFF_T      = 528384,       // t_k = Linv_k m_k (fp32)
  OFF_LOGDET = 530432,
  OFF_SW     = 530448,
  OFF_NUM    = 530464,       // 16*128
  OFF_W      = 532512,       // w[k][n]
  OFF_LOSSK  = 794656,       // 16 per-k loss partials
  OFF_DIFFSQ = 794672,
  OFF_DONE   = 794673,       // int
  OFF_CTR    = 794674,       // int, monotonic (no in-kernel reset)
  // frag-order bf16 arrays (ushort), 2 floats per 4 ushorts:
  OFF_XAH    = 794676,       // X row-side frags: [ng(512)][ec(4)][ks(2)][l(64)][8]
  OFF_XAL    = 1843252,
  OFF_XBH    = 2891828,      // X^T frags: [eg(4)][nb(1024)][l(64)][8]
  OFF_XBL    = 3940404,
  OFF_LBH    = 4988980,      // Linv frags per k: [k][dg(4)][ec(4)][ks(2)][l(64)][8]
  OFF_LBL    = 5120052,
  WS_FLOATS  = 5251124       // ~21 MB
};

__device__ __forceinline__ float bf2f(ushort u) {
  union { unsigned u; float f; } c; c.u = ((unsigned)u) << 16; return c.f;
}
__device__ __forceinline__ ushort f2bf_rne(float f) {
  union { float f; unsigned u; } c; c.f = f;
  unsigned r = c.u + 0x7fffu + ((c.u >> 16) & 1u);
  return (ushort)(r >> 16);
}
__device__ __forceinline__ ushort f2bf_trunc(float f) {
  union { float f; unsigned u; } c; c.f = f; return (ushort)(c.u >> 16);
}

// XOR-quad swizzle for 128x128 LDS matrix.
__device__ __forceinline__ int swz(int r, int c) {
  return (r << 7) + ((((c >> 2) + r) & 31) << 2) + (c & 3);
}

// init state + one-time bf16 hi/lo split of X into frag-order XA (row side)
// and XB (transposed side). Block b handles samples 64b..64b+63.
__global__ __launch_bounds__(256) void k_init_split(const float* __restrict__ x,
                                                    const float* __restrict__ means,
                                                    const float* __restrict__ covs,
                                                    float* __restrict__ ws) {
  __shared__ float xt[64 * 132];
  int b = blockIdx.x, t = threadIdx.x;
  int idx = b * 256 + t;
  for (int i = idx; i < KC * DD * DD; i += 256 * 256) ws[OFF_CS + i] = covs[i];
  if (idx < KC * DD) ws[OFF_CUR_M + idx] = means[idx];
  if (idx == 0) {
    ws[OFF_DIFFSQ] = 0.f;
    ((int*)ws)[OFF_DONE] = 0;
    ((int*)ws)[OFF_CTR]  = 0;
  }
  int n0 = b * 64;
  for (int fi = t; fi < 2048; fi += 256) {
    int n = fi >> 5, q = (fi & 31) * 4;
    *(float4*)&xt[n * 132 + q] = *(const float4*)&x[(size_t)(n0 + n) * DD + q];
  }
  __syncthreads();
  ushort* __restrict__ XAH = (ushort*)(ws + OFF_XAH);
  ushort* __restrict__ XAL = (ushort*)(ws + OFF_XAL);
  ushort* __restrict__ XBH = (ushort*)(ws + OFF_XBH);
  ushort* __restrict__ XBL = (ushort*)(ws + OFF_XBL);
  // XA: n = 32*ng+(l&31), e = 32ec+16ks+8(l>>5)+j
  for (int s = t; s < 1024; s += 256) {
    int l = s & 63, ks = (s >> 6) & 1, ec = (s >> 7) & 3, ngl = (s >> 9) & 1;
    int nl = 32 * ngl + (l & 31);
    int e0 = 32 * ec + 16 * ks + 8 * (l >> 5);
    float vv[8];
    *(float4*)&vv[0] = *(const float4*)&xt[nl * 132 + e0];
    *(float4*)&vv[4] = *(const float4*)&xt[nl * 132 + e0 + 4];
    ushort h[8], lo[8];
    #pragma unroll
    for (int j = 0; j < 8; ++j) {
      h[j]  = f2bf_trunc(vv[j]);
      lo[j] = f2bf_rne(vv[j] - bf2f(h[j]));
    }
    size_t base = ((((size_t)((n0 >> 5) + ngl) * 4 + ec) * 2 + ks) * 64 + l) * 8;
    *(ushort4*)&XAH[base]     = make_ushort4(h[0], h[1], h[2], h[3]);
    *(ushort4*)&XAH[base + 4] = make_ushort4(h[4], h[5], h[6], h[7]);
    *(ushort4*)&XAL[base]     = make_ushort4(lo[0], lo[1], lo[2], lo[3]);
    *(ushort4*)&XAL[base + 4] = make_ushort4(lo[4], lo[5], lo[6], lo[7]);
  }
  // XB: e = 32eg+(l&31), n = 16*nb+8(l>>5)+j
  for (int s = t; s < 1024; s += 256) {
    int l = s & 63, nbl = (s >> 6) & 3, eg = (s >> 8) & 3;
    int e = 32 * eg + (l & 31);
    int nl = 16 * nbl + 8 * (l >> 5);
    ushort h[8], lo[8];
    #pragma unroll
    for (int j = 0; j < 8; ++j) {
      float v = xt[(nl + j) * 132 + e];
      h[j]  = f2bf_trunc(v);
      lo[j] = f2bf_rne(v - bf2f(h[j]));
    }
    size_t base = (((size_t)eg * (NS / 16) + (n0 >> 4) + nbl) * 64 + l) * 8;
    *(ushort4*)&XBH[base]     = make_ushort4(h[0], h[1], h[2], h[3]);
    *(ushort4*)&XBH[base + 4] = make_ushort4(h[4], h[5], h[6], h[7]);
    *(ushort4*)&XBL[base]     = make_ushort4(lo[0], lo[1], lo[2], lo[3]);
    *(ushort4*)&XBL[base + 4] = make_ushort4(lo[4], lo[5], lo[6], lo[7]);
  }
}

// Fused update + Cholesky + triangular inverse. One block per component.
// Phase A: C built in LDS from S/num/sw (or loaded from CS on first call);
//          CS zeroed for next S accumulation; new means + convergence flag.
// Phase B: PANEL=16 wave-synchronous Cholesky (L stays in LDS m).
// Phase C: two-level blocked Linv (L read from LDS via broadcasts), t-solve,
//          frag-order bf16 LB writes.
__global__ __launch_bounds__(256) void k_fused(float* __restrict__ ws, float* __restrict__ dout,
                                               int guarded, int do_update, int write_out,
                                               int accum_diff, int final_pass) {
  if (guarded && ((const int*)ws)[OFF_DONE]) return;
  __shared__ float m[DD * DD];      // 64 KB, swizzled: C then L
  __shared__ float Zs[DD * 132];    // 66 KB: Linv row-major
  __shared__ float Ws[64 * 68];     // 17 KB: GEMM1 temp
  __shared__ float invd_s[DD];
  __shared__ float redbuf[2];
  int k = blockIdx.x, t = threadIdx.x;
  int l = t & 63, wv = t >> 6;
  float* __restrict__ CS = ws + OFF_CS + (size_t)k * DD * DD;

  // ---------- phase A ----------
  if (do_update) {
    float sw = ws[OFF_SW + k];
    float inv = 1.f / sw;
    int e = t & 127, half = t >> 7;
    float me = ws[OFF_CUR_M + k * DD + e];
    float ne = ws[OFF_NUM + k * DD + e];
    const float* __restrict__ cm = ws + OFF_CUR_M + k * DD;
    const float* __restrict__ nm = ws + OFF_NUM + k * DD;
    for (int d = half * 64; d < half * 64 + 64; ++d) {
      float md = cm[d], nd = nm[d];
      float v = (CS[d * DD + e] - md * ne - nd * me + sw * md * me) * inv;
      if (d == e) v += JITTER_;
      m[swz(d, e)] = v;
      CS[d * DD + e] = 0.f;
      if (write_out) dout[1 + KC * DD + (size_t)k * DD * DD + d * DD + e] = v;
    }
    __syncthreads();                 // all reads of old cm done
    if (t < DD) {
      float newm = ne * inv;         // e == t for t < 128
      ws[OFF_CUR_M + k * DD + t] = newm;
      if (write_out) dout[1 + k * DD + t] = newm;
      if (accum_diff) {
        float dm = newm - me;
        float s = dm * dm;
        #pragma unroll
        for (int mk2 = 1; mk2 < 64; mk2 <<= 1) s += __shfl_xor(s, mk2, 64);
        if (l == 0) redbuf[wv] = s;
      }
      ws[OFF_NUM + k * DD + t] = 0.f;
    }
    if (t == 0) {
      ws[OFF_SW + k] = 0.f;
      if (final_pass) ws[OFF_LOSSK + k] = 0.f;
    }
    __syncthreads();
    if (accum_diff && t == 0) {
      atomicAdd(&ws[OFF_DIFFSQ], redbuf[0] + redbuf[1]);
      __threadfence();
      int old = atomicAdd((int*)ws + OFF_CTR, 1);
      if ((old & (KC - 1)) == KC - 1) {          // last arriving block this call
        float v = atomicAdd(&ws[OFF_DIFFSQ], 0.f);
        if (v <= EPS2_) atomicExch((int*)ws + OFF_DONE, 1);
        atomicExch(&ws[OFF_DIFFSQ], 0.f);
      }
    }
  } else {
    for (int i = t; i < DD * DD; i += 256) {
      m[swz(i >> 7, i & 127)] = CS[i];
      CS[i] = 0.f;
    }
    if (t < DD) ws[OFF_NUM + k * DD + t] = 0.f;
    if (t == 0) ws[OFF_SW + k] = 0.f;
  }
  __syncthreads();

  // ---------- phase B: Cholesky, PANEL=16 wave-sync (round-8 proven) ----------
  for (int P = 0; P < DD; P += 16) {
    if (wv == 0) {
      int ra = P + l, rb = P + 64 + l;
      bool va = ra < DD, vb = rb < DD;
      float A[16], B[16];
      if (va) {
        #pragma unroll
        for (int q = 0; q < 4; ++q) {
          float4 v = *(const float4*)&m[swz(ra, P + 4 * q)];
          A[4*q+0] = v.x; A[4*q+1] = v.y; A[4*q+2] = v.z; A[4*q+3] = v.w;
        }
      }
      if (vb) {
        #pragma unroll
        for (int q = 0; q < 4; ++q) {
          float4 v = *(const float4*)&m[swz(rb, P + 4 * q)];
          B[4*q+0] = v.x; B[4*q+1] = v.y; B[4*q+2] = v.z; B[4*q+3] = v.w;
        }
      }
      #pragma unroll
      for (int jj = 0; jj < 16; ++jj) {
        float dj = __shfl(A[jj], jj, 64);
        float sj = sqrtf(dj);
        float inv = 1.f / sj;
        if (va) {
          if (l == jj) A[jj] = sj;
          else if (l > jj) A[jj] *= inv;
        }
        if (vb) B[jj] *= inv;
        #pragma unroll
        for (int jj2 = jj + 1; jj2 < 16; ++jj2) {
          float c = __shfl(A[jj], jj2, 64);
          if (va && l > jj) A[jj2] -= A[jj] * c;
          if (vb) B[jj2] -= B[jj] * c;
        }
      }
      if (va) {
        #pragma unroll
        for (int q = 0; q < 4; ++q)
          *(float4*)&m[swz(ra, P + 4 * q)] = make_float4(A[4*q], A[4*q+1], A[4*q+2], A[4*q+3]);
      }
      if (vb) {
        #pragma unroll
        for (int q = 0; q < 4; ++q)
          *(float4*)&m[swz(rb, P + 4 * q)] = make_float4(B[4*q], B[4*q+1], B[4*q+2], B[4*q+3]);
      }
    }
    __syncthreads();
    int R0 = P + 16;
    if (R0 < DD) {
      int s = DD - R0;
      int tq = R0 + (t & 31);
      for (int b = 0; b < s; b += 32) {
        int q = tq + b;
        if (q < DD) {
          float lq[16];
          #pragma unroll
          for (int p4 = 0; p4 < 4; ++p4) {
            float4 v = *(const float4*)&m[swz(q, P + 4 * p4)];
            lq[4*p4+0] = v.x; lq[4*p4+1] = v.y; lq[4*p4+2] = v.z; lq[4*p4+3] = v.w;
          }
          for (int i = R0 + (t >> 5); i < DD; i += 8) {
            float a = m[swz(i, q)];
            #pragma unroll
            for (int p4 = 0; p4 < 4; ++p4) {
              float4 v = *(const float4*)&m[swz(i, P + 4 * p4)];
              a -= v.x * lq[4*p4+0] + v.y * lq[4*p4+1] + v.z * lq[4*p4+2] + v.w * lq[4*p4+3];
            }
            m[swz(i, q)] = a;
          }
        }
      }
    }
    __syncthreads();
  }

  if (t < DD) invd_s[t] = 1.f / m[swz(t, t)];
  if (final_pass && t == 0) {
    float ld = 0.f;
    for (int i = 0; i < DD; ++i) ld += logf(m[swz(i, i)]);
    ws[OFF_LOGDET + k] = 2.f * ld;
  }
  __syncthreads();

  // ---------- phase C: two-level trinv (L read from LDS m) ----------
  if (t < 128) {
    int h = t >> 6, j = t & 63;      // h uniform per wave -> broadcast reads
    float acc[64];
    #pragma unroll
    for (int i = 0; i < 64; ++i) acc[i] = 0.f;
    #pragma unroll
    for (int p = 0; p < 64; ++p) {
      float zp = (((p == j) ? 1.f : 0.f) - acc[p]) * invd_s[h * 64 + p];
      Zs[(h * 64 + p) * 132 + h * 64 + j] = zp;
      #pragma unroll
      for (int i = p + 1; i < 64; ++i)
        acc[i] += m[swz(h * 64 + i, h * 64 + p)] * zp;
    }
  } else {
    for (int s = t - 128; s < 4096; s += 128)
      Zs[(s >> 6) * 132 + 64 + (s & 63)] = 0.f;   // upper-right zero block
  }
  __syncthreads();
  int i0 = (t & 15) * 4, j0 = (t >> 4) * 4;
  {  // GEMM1: W = C * Ainv, C[i][q] = L[64+i][q] = m[swz(64+i, q)]
    float acc4[4][4] = {};
    for (int q = 0; q < 64; ++q) {
      float av[4];
      #pragma unroll
      for (int r = 0; r < 4; ++r) av[r] = m[swz(64 + i0 + r, q)];
      float4 b = *(const float4*)&Zs[q * 132 + j0];
      float bv[4] = {b.x, b.y, b.z, b.w};
      #pragma unroll
      for (int r = 0; r < 4; ++r)
        #pragma unroll
        for (int c = 0; c < 4; ++c) acc4[r][c] += av[r] * bv[c];
    }
    #pragma unroll
    for (int r = 0; r < 4; ++r)
      #pragma unroll
      for (int c = 0; c < 4; ++c) Ws[(i0 + r) * 68 + j0 + c] = acc4[r][c];
  }
  __syncthreads();
  {  // GEMM2: Linv21 = -Binv * W
    float acc4[4][4] = {};
    for (int q0 = 0; q0 < 64; q0 += 4) {
      float4 bi[4], wq[4];
      #pragma unroll
      for (int r = 0; r < 4; ++r)
        bi[r] = *(const float4*)&Zs[(64 + i0 + r) * 132 + 64 + q0];
      #pragma unroll
      for (int s = 0; s < 4; ++s)
        wq[s] = *(const float4*)&Ws[(q0 + s) * 68 + j0];
      #pragma unroll
      for (int r = 0; r < 4; ++r) {
        float br[4] = {bi[r].x, bi[r].y, bi[r].z, bi[r].w};
        #pragma unroll
        for (int s = 0; s < 4; ++s) {
          float wv2[4] = {wq[s].x, wq[s].y, wq[s].z, wq[s].w};
          #pragma unroll
          for (int c = 0; c < 4; ++c) acc4[r][c] += br[s] * wv2[c];
        }
      }
    }
    #pragma unroll
    for (int r = 0; r < 4; ++r)
      #pragma unroll
      for (int c = 0; c < 4; ++c) Zs[(64 + i0 + r) * 132 + j0 + c] = -acc4[r][c];
  }
  __syncthreads();
  if (t < 128) {   // t = Linv * m  (NEW means, already written in phase A)
    const float* __restrict__ mk = ws + OFF_CUR_M + k * DD;
    float s0 = 0.f;
    for (int e = 0; e < DD; e += 4) {
      float4 z = *(const float4*)&Zs[t * 132 + e];
      s0 += z.x * mk[e] + z.y * mk[e + 1] + z.z * mk[e + 2] + z.w * mk[e + 3];
    }
    ws[OFF_T + k * DD + t] = s0;
  }
  // frag-order bf16 writes: d=32dg+(l&31), e=32ec+16ks+8(l>>5)+j2
  ushort* __restrict__ LBH = (ushort*)(ws + OFF_LBH) + (size_t)k * 16384;
  ushort* __restrict__ LBL = (ushort*)(ws + OFF_LBL) + (size_t)k * 16384;
  for (int s = t; s < 16384; s += 256) {
    int j2 = s & 7, ll = (s >> 3) & 63, ks2 = (s >> 9) & 1, ec = (s >> 10) & 3, dg = (s >> 12) & 3;
    int d = 32 * dg + (ll & 31);
    int e = 32 * ec + 16 * ks2 + 8 * (ll >> 5) + j2;
    float v = Zs[d * 132 + e];
    ushort hh = f2bf_trunc(v);
    LBH[s] = hh;
    LBL[s] = f2bf_rne(v - bf2f(hh));
  }
}

// w[n,k] = ||X Linv^T - t||^2. Block: 128 samples x full 128 d, 4 waves.
__global__ __launch_bounds__(256) void k_quad(float* __restrict__ ws,
                                              const float* __restrict__ wts,
                                              int guarded, int final_pass) {
  if (guarded && ((const int*)ws)[OFF_DONE]) return;
  __shared__ float warr[128];
  int k = blockIdx.y, bx = blockIdx.x, t = threadIdx.x;
  int l = t & 63, wv = t >> 6;
  int n0 = bx * 128;
  const ushort* __restrict__ XAH = (const ushort*)(ws + OFF_XAH);
  const ushort* __restrict__ XAL = (const ushort*)(ws + OFF_XAL);
  const ushort* __restrict__ LBH = (const ushort*)(ws + OFF_LBH) + (size_t)k * 16384;
  const ushort* __restrict__ LBL = (const ushort*)(ws + OFF_LBL) + (size_t)k * 16384;
  f32x16 acc[4] = {};
  size_t ng4 = (size_t)(4 * bx + wv) * 4;
  #pragma unroll
  for (int ec = 0; ec < 4; ++ec) {
    #pragma unroll
    for (int ks = 0; ks < 2; ++ks) {
      size_t aoff = (((ng4 + ec) * 2 + ks) * 64 + l) * 8;
      bf16x8 ah = *(const bf16x8*)&XAH[aoff];
      bf16x8 al = *(const bf16x8*)&XAL[aoff];
      #pragma unroll
      for (int dg = 0; dg < 4; ++dg) {
        size_t boff = ((((size_t)dg * 4 + ec) * 2 + ks) * 64 + l) * 8;
        bf16x8 bh = *(const bf16x8*)&LBH[boff];
        bf16x8 bl = *(const bf16x8*)&LBL[boff];
        acc[dg] = __builtin_amdgcn_mfma_f32_32x32x16_bf16(ah, bh, acc[dg], 0, 0, 0);
        acc[dg] = __builtin_amdgcn_mfma_f32_32x32x16_bf16(ah, bl, acc[dg], 0, 0, 0);
        acc[dg] = __builtin_amdgcn_mfma_f32_32x32x16_bf16(al, bh, acc[dg], 0, 0, 0);
      }
    }
  }
  float tv[4];
  #pragma unroll
  for (int c = 0; c < 4; ++c) tv[c] = ws[OFF_T + k * DD + 32 * c + (l & 31)];
  float part[16];
  #pragma unroll
  for (int r = 0; r < 16; ++r) {
    float s = 0.f;
    #pragma unroll
    for (int c = 0; c < 4; ++c) { float d = acc[c][r] - tv[c]; s += d * d; }
    part[r] = s;
  }
  #pragma unroll
  for (int mk2 = 1; mk2 < 32; mk2 <<= 1)
    #pragma unroll
    for (int r = 0; r < 16; ++r) part[r] += __shfl_xor(part[r], mk2, 64);
  int h = l >> 5;
  if ((l & 31) < 16) {
    int r = l & 31;
    int row = (r & 3) + 8 * (r >> 2) + 4 * h + 32 * wv;   // verified C/D layout
    warr[row] = part[r];
    ws[OFF_W + k * NS + n0 + row] = part[r];
  }
  __syncthreads();
  if (!final_pass) {
    if (t < 128) {
      int d = t;
      int e_ec = d >> 5, e_ks = (d >> 4) & 1, e_h = (d >> 3) & 1, e_j = d & 7;
      float s = 0.f;
      for (int n = 0; n < 128; ++n) {
        size_t a = ((((size_t)(4 * bx + (n >> 5)) * 4 + e_ec) * 2 + e_ks) * 64 +
                    ((e_h << 5) | (n & 31))) * 8 + e_j;
        s += warr[n] * (bf2f(XAH[a]) + bf2f(XAL[a]));
      }
      atomicAdd(&ws[OFF_NUM + k * DD + d], s);
    } else if (t == 128) {
      float s = 0.f;
      for (int n = 0; n < 128; ++n) s += warr[n];
      atomicAdd(&ws[OFF_SW + k], s);
    }
  } else {
    if (t < 64) {
      float s = warr[t] + warr[t + 64];
      #pragma unroll
      for (int mk2 = 1; mk2 < 64; mk2 <<= 1) s += __shfl_xor(s, mk2, 64);
      if (t == 0) atomicAdd(&ws[OFF_LOSSK + k], 0.5f * wts[k] * s);
    }
  }
}

// S_k += (w.X)^T X over NCHUNK samples; operands from frag-order XB arrays.
__global__ __launch_bounds__(256) void k_scatter(float* __restrict__ ws, int guarded) {
  if (guarded && ((const int*)ws)[OFF_DONE]) return;
  int k = blockIdx.y, chunk = blockIdx.x, t = threadIdx.x;
  int l = t & 63, dg = t >> 6;
  const ushort* __restrict__ XBH = (const ushort*)(ws + OFF_XBH);
  const ushort* __restrict__ XBL = (const ushort*)(ws + OFF_XBL);
  const float* __restrict__ wp = ws + OFF_W + k * NS + chunk * NCHUNK;
  f32x16 acc[4] = {};
  int nb0 = chunk * (NCHUNK / 16);
  int ko = (l >> 5) * 8;
  for (int st = 0; st < NCHUNK / 16; ++st) {
    size_t aoff = (((size_t)dg * (NS / 16) + nb0 + st) * 64 + l) * 8;
    bf16x8 th = *(const bf16x8*)&XBH[aoff];
    bf16x8 tl = *(const bf16x8*)&XBL[aoff];
    float4 w0 = *(const float4*)&wp[16 * st + ko];
    float4 w1 = *(const float4*)&wp[16 * st + ko + 4];
    float wj[8] = {w0.x, w0.y, w0.z, w0.w, w1.x, w1.y, w1.z, w1.w};
    bf16x8 ah, al;
    #pragma unroll
    for (int j = 0; j < 8; ++j) {
      float xf = bf2f((ushort)th[j]) + bf2f((ushort)tl[j]);
      float zf = wj[j] * xf;
      union { float f; unsigned u; } cz; cz.f = zf;
      ah[j] = (short)(ushort)(cz.u >> 16);
      union { unsigned u; float f; } ch; ch.u = cz.u & 0xffff0000u;
      al[j] = (short)f2bf_rne(zf - ch.f);
    }
    #pragma unroll
    for (int eg = 0; eg < 4; ++eg) {
      size_t boff = (((size_t)eg * (NS / 16) + nb0 + st) * 64 + l) * 8;
      bf16x8 bh = *(const bf16x8*)&XBH[boff];
      bf16x8 bl = *(const bf16x8*)&XBL[boff];
      acc[eg] = __builtin_amdgcn_mfma_f32_32x32x16_bf16(ah, bh, acc[eg], 0, 0, 0);
      acc[eg] = __builtin_amdgcn_mfma_f32_32x32x16_bf16(ah, bl, acc[eg], 0, 0, 0);
      acc[eg] = __builtin_amdgcn_mfma_f32_32x32x16_bf16(al, bh, acc[eg], 0, 0, 0);
    }
  }
  float* __restrict__ S = ws + OFF_CS + (size_t)k * DD * DD;
  int h = l >> 5;
  #pragma unroll
  for (int eg = 0; eg < 4; ++eg) {
    int e = 32 * eg + (l & 31);
    #pragma unroll
    for (int r = 0; r < 16; ++r) {
      int drow = 32 * dg + (r & 3) + 8 * (r >> 2) + 4 * h;
      atomicAdd(&S[drow * DD + e], acc[eg][r]);
    }
  }
}

__global__ void k_lossfin(const float* __restrict__ weights, const float* __restrict__ ws,
                          float* __restrict__ dout) {
  if (threadIdx.x == 0 && blockIdx.x == 0) {
    float base = 0.f;
    for (int k = 0; k < KC; ++k)
      base += weights[k] * 0.5f * (float)NS * ((float)DD * LOG_2PI_ + ws[OFF_LOGDET + k])
            + ws[OFF_LOSSK + k];
    dout[0] = base;
  }
}

extern "C" void kernel_launch(void* const* d_in, const int* in_sizes, int n_in,
                              void* d_out, int out_size, void* d_ws, size_t ws_size,
                              hipStream_t stream) {
  const float* x       = (const float*)d_in[0];
  const float* means   = (const float*)d_in[1];
  const float* covs    = (const float*)d_in[2];
  const float* weights = (const float*)d_in[3];
  float* out = (float*)d_out;
  float* ws  = (float*)d_ws;

  hipLaunchKernelGGL(k_init_split, dim3(NS / 64), dim3(256), 0, stream, x, means, covs, ws);
  // first factorization of the initial covariances (no update phase)
  hipLaunchKernelGGL(k_fused, dim3(16), dim3(256), 0, stream, ws, out, 0, 0, 0, 0, 0);

  // 8 guarded EM iterations: w accumulation, then fused update+chol+trinv
  for (int u = 0; u < 8; ++u) {
    hipLaunchKernelGGL(k_quad,    dim3(128, 16), dim3(256), 0, stream, ws, weights, 1, 0);
    hipLaunchKernelGGL(k_scatter, dim3(NS / NCHUNK, 16), dim3(256), 0, stream, ws, 1);
    hipLaunchKernelGGL(k_fused,   dim3(16), dim3(256), 0, stream, ws, out, 1, 1, 0, 1, 0);
  }

  // final (always-executed) update + chol/trinv of c_fin, then loss
  hipLaunchKernelGGL(k_quad,    dim3(128, 16), dim3(256), 0, stream, ws, weights, 0, 0);
  hipLaunchKernelGGL(k_scatter, dim3(NS / NCHUNK, 16), dim3(256), 0, stream, ws, 0);
  hipLaunchKernelGGL(k_fused,   dim3(16), dim3(256), 0, stream, ws, out, 0, 1, 1, 0, 1);
  hipLaunchKernelGGL(k_quad,    dim3(128, 16), dim3(256), 0, stream, ws, weights, 0, 1);
  hipLaunchKernelGGL(k_lossfin, dim3(1), dim3(64), 0, stream, weights, ws, out);
}

// Round 11
// 1262.481 us; speedup vs baseline: 1.3101x; 1.3101x over previous
//
#include <hip/hip_runtime.h>
#include <math.h>

// GaussianMixtureLayer: EM loop (<=8 iters, device-side convergence flag) +
// final update + Gaussian log-prob loss. Heavy GEMMs on bf16 MFMA (hi/lo
// 3-term split), operands in FRAGMENT ORDER (wave-contiguous dwordx4 loads).
//   k_quad   : Y = X Linv^T, w = ||y - t||^2 (pure MFMA + w-write; num/sw
//              moved into k_scatter where z=w*x is already materialized)
//   k_scatter: S_k = (w.X)^T X + fused num/sw accumulation. NCHUNK=512:
//              512 blocks = 2/CU (NCHUNK=2048 ran half the machine idle ->
//              132us; occupancy beats flush-amortization here)
//   k_fused  : update + Cholesky + two-level trinv in one kernel; C and L
//              never leave LDS (the chol-class kernels were pinned at ~85us
//              by C/LT global round-trips at 16-block latency-bound rates)

#define NS 16384
#define DD 128
#define KC 16
#define JITTER_ 1e-6f
#define EPS2_ 1e-6f            // (1e-3)^2 Frobenius convergence check
#define LOG_2PI_ 1.8378770664093454f
#define NCHUNK 512             // scatter samples per block

typedef __attribute__((ext_vector_type(8))) short bf16x8;
typedef __attribute__((ext_vector_type(16))) float f32x16;

// workspace float offsets
enum : int {
  OFF_CUR_M  = 0,            // 16*128
  OFF_CS     = 2048,         // 16*128*128  S accumulator (zeroed by k_fused)
  OFF_T      = 528384,       // t_k = Linv_k m_k (fp32)
  OFF_LOGDET = 530432,
  OFF_SW     = 530448,
  OFF_NUM    = 530464,       // 16*128
  OFF_W      = 532512,       // w[k][n]
  OFF_LOSSK  = 794656,       // 16 per-k loss partials
  OFF_DIFFSQ = 794672,
  OFF_DONE   = 794673,       // int
  OFF_CTR    = 794674,       // int, monotonic (no in-kernel reset)
  // frag-order bf16 arrays (ushort), 2 floats per 4 ushorts:
  OFF_XAH    = 794676,       // X row-side frags: [ng(512)][ec(4)][ks(2)][l(64)][8]
  OFF_XAL    = 1843252,
  OFF_XBH    = 2891828,      // X^T frags: [eg(4)][nb(1024)][l(64)][8]
  OFF_XBL    = 3940404,
  OFF_LBH    = 4988980,      // Linv frags per k: [k][dg(4)][ec(4)][ks(2)][l(64)][8]
  OFF_LBL    = 5120052,
  WS_FLOATS  = 5251124       // ~21 MB
};

__device__ __forceinline__ float bf2f(ushort u) {
  union { unsigned u; float f; } c; c.u = ((unsigned)u) << 16; return c.f;
}
__device__ __forceinline__ ushort f2bf_rne(float f) {
  union { float f; unsigned u; } c; c.f = f;
  unsigned r = c.u + 0x7fffu + ((c.u >> 16) & 1u);
  return (ushort)(r >> 16);
}
__device__ __forceinline__ ushort f2bf_trunc(float f) {
  union { float f; unsigned u; } c; c.f = f; return (ushort)(c.u >> 16);
}

// XOR-quad swizzle for 128x128 LDS matrix.
__device__ __forceinline__ int swz(int r, int c) {
  return (r << 7) + ((((c >> 2) + r) & 31) << 2) + (c & 3);
}

// init state + one-time bf16 hi/lo split of X into frag-order XA (row side)
// and XB (transposed side). Block b handles samples 64b..64b+63.
__global__ __launch_bounds__(256) void k_init_split(const float* __restrict__ x,
                                                    const float* __restrict__ means,
                                                    const float* __restrict__ covs,
                                                    float* __restrict__ ws) {
  __shared__ float xt[64 * 132];
  int b = blockIdx.x, t = threadIdx.x;
  int idx = b * 256 + t;
  for (int i = idx; i < KC * DD * DD; i += 256 * 256) ws[OFF_CS + i] = covs[i];
  if (idx < KC * DD) ws[OFF_CUR_M + idx] = means[idx];
  if (idx == 0) {
    ws[OFF_DIFFSQ] = 0.f;
    ((int*)ws)[OFF_DONE] = 0;
    ((int*)ws)[OFF_CTR]  = 0;
  }
  int n0 = b * 64;
  for (int fi = t; fi < 2048; fi += 256) {
    int n = fi >> 5, q = (fi & 31) * 4;
    *(float4*)&xt[n * 132 + q] = *(const float4*)&x[(size_t)(n0 + n) * DD + q];
  }
  __syncthreads();
  ushort* __restrict__ XAH = (ushort*)(ws + OFF_XAH);
  ushort* __restrict__ XAL = (ushort*)(ws + OFF_XAL);
  ushort* __restrict__ XBH = (ushort*)(ws + OFF_XBH);
  ushort* __restrict__ XBL = (ushort*)(ws + OFF_XBL);
  // XA: n = 32*ng+(l&31), e = 32ec+16ks+8(l>>5)+j
  for (int s = t; s < 1024; s += 256) {
    int l = s & 63, ks = (s >> 6) & 1, ec = (s >> 7) & 3, ngl = (s >> 9) & 1;
    int nl = 32 * ngl + (l & 31);
    int e0 = 32 * ec + 16 * ks + 8 * (l >> 5);
    float vv[8];
    *(float4*)&vv[0] = *(const float4*)&xt[nl * 132 + e0];
    *(float4*)&vv[4] = *(const float4*)&xt[nl * 132 + e0 + 4];
    ushort h[8], lo[8];
    #pragma unroll
    for (int j = 0; j < 8; ++j) {
      h[j]  = f2bf_trunc(vv[j]);
      lo[j] = f2bf_rne(vv[j] - bf2f(h[j]));
    }
    size_t base = ((((size_t)((n0 >> 5) + ngl) * 4 + ec) * 2 + ks) * 64 + l) * 8;
    *(ushort4*)&XAH[base]     = make_ushort4(h[0], h[1], h[2], h[3]);
    *(ushort4*)&XAH[base + 4] = make_ushort4(h[4], h[5], h[6], h[7]);
    *(ushort4*)&XAL[base]     = make_ushort4(lo[0], lo[1], lo[2], lo[3]);
    *(ushort4*)&XAL[base + 4] = make_ushort4(lo[4], lo[5], lo[6], lo[7]);
  }
  // XB: e = 32eg+(l&31), n = 16*nb+8(l>>5)+j
  for (int s = t; s < 1024; s += 256) {
    int l = s & 63, nbl = (s >> 6) & 3, eg = (s >> 8) & 3;
    int e = 32 * eg + (l & 31);
    int nl = 16 * nbl + 8 * (l >> 5);
    ushort h[8], lo[8];
    #pragma unroll
    for (int j = 0; j < 8; ++j) {
      float v = xt[(nl + j) * 132 + e];
      h[j]  = f2bf_trunc(v);
      lo[j] = f2bf_rne(v - bf2f(h[j]));
    }
    size_t base = (((size_t)eg * (NS / 16) + (n0 >> 4) + nbl) * 64 + l) * 8;
    *(ushort4*)&XBH[base]     = make_ushort4(h[0], h[1], h[2], h[3]);
    *(ushort4*)&XBH[base + 4] = make_ushort4(h[4], h[5], h[6], h[7]);
    *(ushort4*)&XBL[base]     = make_ushort4(lo[0], lo[1], lo[2], lo[3]);
    *(ushort4*)&XBL[base + 4] = make_ushort4(lo[4], lo[5], lo[6], lo[7]);
  }
}

// Fused update + Cholesky + triangular inverse. One block per component.
__global__ __launch_bounds__(256) void k_fused(float* __restrict__ ws, float* __restrict__ dout,
                                               int guarded, int do_update, int write_out,
                                               int accum_diff, int final_pass) {
  if (guarded && ((const int*)ws)[OFF_DONE]) return;
  __shared__ float m[DD * DD];      // 64 KB, swizzled: C then L
  __shared__ float Zs[DD * 132];    // 66 KB: Linv row-major
  __shared__ float Ws[64 * 68];     // 17 KB: GEMM1 temp
  __shared__ float invd_s[DD];
  __shared__ float redbuf[2];
  int k = blockIdx.x, t = threadIdx.x;
  int l = t & 63, wv = t >> 6;
  float* __restrict__ CS = ws + OFF_CS + (size_t)k * DD * DD;

  // ---------- phase A ----------
  if (do_update) {
    float sw = ws[OFF_SW + k];
    float inv = 1.f / sw;
    int e = t & 127, half = t >> 7;
    float me = ws[OFF_CUR_M + k * DD + e];
    float ne = ws[OFF_NUM + k * DD + e];
    const float* __restrict__ cm = ws + OFF_CUR_M + k * DD;
    const float* __restrict__ nm = ws + OFF_NUM + k * DD;
    for (int d = half * 64; d < half * 64 + 64; ++d) {
      float md = cm[d], nd = nm[d];
      float v = (CS[d * DD + e] - md * ne - nd * me + sw * md * me) * inv;
      if (d == e) v += JITTER_;
      m[swz(d, e)] = v;
      CS[d * DD + e] = 0.f;
      if (write_out) dout[1 + KC * DD + (size_t)k * DD * DD + d * DD + e] = v;
    }
    __syncthreads();                 // all reads of old cm done
    if (t < DD) {
      float newm = ne * inv;         // e == t for t < 128
      ws[OFF_CUR_M + k * DD + t] = newm;
      if (write_out) dout[1 + k * DD + t] = newm;
      if (accum_diff) {
        float dm = newm - me;
        float s = dm * dm;
        #pragma unroll
        for (int mk2 = 1; mk2 < 64; mk2 <<= 1) s += __shfl_xor(s, mk2, 64);
        if (l == 0) redbuf[wv] = s;
      }
      ws[OFF_NUM + k * DD + t] = 0.f;
    }
    if (t == 0) {
      ws[OFF_SW + k] = 0.f;
      if (final_pass) ws[OFF_LOSSK + k] = 0.f;
    }
    __syncthreads();
    if (accum_diff && t == 0) {
      atomicAdd(&ws[OFF_DIFFSQ], redbuf[0] + redbuf[1]);
      __threadfence();
      int old = atomicAdd((int*)ws + OFF_CTR, 1);
      if ((old & (KC - 1)) == KC - 1) {
        float v = atomicAdd(&ws[OFF_DIFFSQ], 0.f);
        if (v <= EPS2_) atomicExch((int*)ws + OFF_DONE, 1);
        atomicExch(&ws[OFF_DIFFSQ], 0.f);
      }
    }
  } else {
    for (int i = t; i < DD * DD; i += 256) {
      m[swz(i >> 7, i & 127)] = CS[i];
      CS[i] = 0.f;
    }
    if (t < DD) ws[OFF_NUM + k * DD + t] = 0.f;
    if (t == 0) ws[OFF_SW + k] = 0.f;
  }
  __syncthreads();

  // ---------- phase B: Cholesky, PANEL=16 wave-sync ----------
  for (int P = 0; P < DD; P += 16) {
    if (wv == 0) {
      int ra = P + l, rb = P + 64 + l;
      bool va = ra < DD, vb = rb < DD;
      float A[16], B[16];
      if (va) {
        #pragma unroll
        for (int q = 0; q < 4; ++q) {
          float4 v = *(const float4*)&m[swz(ra, P + 4 * q)];
          A[4*q+0] = v.x; A[4*q+1] = v.y; A[4*q+2] = v.z; A[4*q+3] = v.w;
        }
      }
      if (vb) {
        #pragma unroll
        for (int q = 0; q < 4; ++q) {
          float4 v = *(const float4*)&m[swz(rb, P + 4 * q)];
          B[4*q+0] = v.x; B[4*q+1] = v.y; B[4*q+2] = v.z; B[4*q+3] = v.w;
        }
      }
      #pragma unroll
      for (int jj = 0; jj < 16; ++jj) {
        float dj = __shfl(A[jj], jj, 64);
        float sj = sqrtf(dj);
        float inv = 1.f / sj;
        if (va) {
          if (l == jj) A[jj] = sj;
          else if (l > jj) A[jj] *= inv;
        }
        if (vb) B[jj] *= inv;
        #pragma unroll
        for (int jj2 = jj + 1; jj2 < 16; ++jj2) {
          float c = __shfl(A[jj], jj2, 64);
          if (va && l > jj) A[jj2] -= A[jj] * c;
          if (vb) B[jj2] -= B[jj] * c;
        }
      }
      if (va) {
        #pragma unroll
        for (int q = 0; q < 4; ++q)
          *(float4*)&m[swz(ra, P + 4 * q)] = make_float4(A[4*q], A[4*q+1], A[4*q+2], A[4*q+3]);
      }
      if (vb) {
        #pragma unroll
        for (int q = 0; q < 4; ++q)
          *(float4*)&m[swz(rb, P + 4 * q)] = make_float4(B[4*q], B[4*q+1], B[4*q+2], B[4*q+3]);
      }
    }
    __syncthreads();
    int R0 = P + 16;
    if (R0 < DD) {
      int s = DD - R0;
      int tq = R0 + (t & 31);
      for (int b = 0; b < s; b += 32) {
        int q = tq + b;
        if (q < DD) {
          float lq[16];
          #pragma unroll
          for (int p4 = 0; p4 < 4; ++p4) {
            float4 v = *(const float4*)&m[swz(q, P + 4 * p4)];
            lq[4*p4+0] = v.x; lq[4*p4+1] = v.y; lq[4*p4+2] = v.z; lq[4*p4+3] = v.w;
          }
          for (int i = R0 + (t >> 5); i < DD; i += 8) {
            float a = m[swz(i, q)];
            #pragma unroll
            for (int p4 = 0; p4 < 4; ++p4) {
              float4 v = *(const float4*)&m[swz(i, P + 4 * p4)];
              a -= v.x * lq[4*p4+0] + v.y * lq[4*p4+1] + v.z * lq[4*p4+2] + v.w * lq[4*p4+3];
            }
            m[swz(i, q)] = a;
          }
        }
      }
    }
    __syncthreads();
  }

  if (t < DD) invd_s[t] = 1.f / m[swz(t, t)];
  if (final_pass && t == 0) {
    float ld = 0.f;
    for (int i = 0; i < DD; ++i) ld += logf(m[swz(i, i)]);
    ws[OFF_LOGDET + k] = 2.f * ld;
  }
  __syncthreads();

  // ---------- phase C: two-level trinv (L read from LDS m) ----------
  if (t < 128) {
    int h = t >> 6, j = t & 63;
    float acc[64];
    #pragma unroll
    for (int i = 0; i < 64; ++i) acc[i] = 0.f;
    #pragma unroll
    for (int p = 0; p < 64; ++p) {
      float zp = (((p == j) ? 1.f : 0.f) - acc[p]) * invd_s[h * 64 + p];
      Zs[(h * 64 + p) * 132 + h * 64 + j] = zp;
      #pragma unroll
      for (int i = p + 1; i < 64; ++i)
        acc[i] += m[swz(h * 64 + i, h * 64 + p)] * zp;
    }
  } else {
    for (int s = t - 128; s < 4096; s += 128)
      Zs[(s >> 6) * 132 + 64 + (s & 63)] = 0.f;
  }
  __syncthreads();
  int i0 = (t & 15) * 4, j0 = (t >> 4) * 4;
  {  // GEMM1: W = C * Ainv
    float acc4[4][4] = {};
    for (int q = 0; q < 64; ++q) {
      float av[4];
      #pragma unroll
      for (int r = 0; r < 4; ++r) av[r] = m[swz(64 + i0 + r, q)];
      float4 b = *(const float4*)&Zs[q * 132 + j0];
      float bv[4] = {b.x, b.y, b.z, b.w};
      #pragma unroll
      for (int r = 0; r < 4; ++r)
        #pragma unroll
        for (int c = 0; c < 4; ++c) acc4[r][c] += av[r] * bv[c];
    }
    #pragma unroll
    for (int r = 0; r < 4; ++r)
      #pragma unroll
      for (int c = 0; c < 4; ++c) Ws[(i0 + r) * 68 + j0 + c] = acc4[r][c];
  }
  __syncthreads();
  {  // GEMM2: Linv21 = -Binv * W
    float acc4[4][4] = {};
    for (int q0 = 0; q0 < 64; q0 += 4) {
      float4 bi[4], wq[4];
      #pragma unroll
      for (int r = 0; r < 4; ++r)
        bi[r] = *(const float4*)&Zs[(64 + i0 + r) * 132 + 64 + q0];
      #pragma unroll
      for (int s = 0; s < 4; ++s)
        wq[s] = *(const float4*)&Ws[(q0 + s) * 68 + j0];
      #pragma unroll
      for (int r = 0; r < 4; ++r) {
        float br[4] = {bi[r].x, bi[r].y, bi[r].z, bi[r].w};
        #pragma unroll
        for (int s = 0; s < 4; ++s) {
          float wv2[4] = {wq[s].x, wq[s].y, wq[s].z, wq[s].w};
          #pragma unroll
          for (int c = 0; c < 4; ++c) acc4[r][c] += br[s] * wv2[c];
        }
      }
    }
    #pragma unroll
    for (int r = 0; r < 4; ++r)
      #pragma unroll
      for (int c = 0; c < 4; ++c) Zs[(64 + i0 + r) * 132 + j0 + c] = -acc4[r][c];
  }
  __syncthreads();
  if (t < 128) {   // t = Linv * m  (NEW means)
    const float* __restrict__ mk = ws + OFF_CUR_M + k * DD;
    float s0 = 0.f;
    for (int e = 0; e < DD; e += 4) {
      float4 z = *(const float4*)&Zs[t * 132 + e];
      s0 += z.x * mk[e] + z.y * mk[e + 1] + z.z * mk[e + 2] + z.w * mk[e + 3];
    }
    ws[OFF_T + k * DD + t] = s0;
  }
  // frag-order bf16 writes
  ushort* __restrict__ LBH = (ushort*)(ws + OFF_LBH) + (size_t)k * 16384;
  ushort* __restrict__ LBL = (ushort*)(ws + OFF_LBL) + (size_t)k * 16384;
  for (int s = t; s < 16384; s += 256) {
    int j2 = s & 7, ll = (s >> 3) & 63, ks2 = (s >> 9) & 1, ec = (s >> 10) & 3, dg = (s >> 12) & 3;
    int d = 32 * dg + (ll & 31);
    int e = 32 * ec + 16 * ks2 + 8 * (ll >> 5) + j2;
    float v = Zs[d * 132 + e];
    ushort hh = f2bf_trunc(v);
    LBH[s] = hh;
    LBL[s] = f2bf_rne(v - bf2f(hh));
  }
}

// w[n,k] = ||X Linv^T - t||^2. Block: 128 samples x full 128 d, 4 waves.
// Pure MFMA + w-write (num/sw accumulation moved to k_scatter).
__global__ __launch_bounds__(256) void k_quad(float* __restrict__ ws,
                                              const float* __restrict__ wts,
                                              int guarded, int final_pass) {
  if (guarded && ((const int*)ws)[OFF_DONE]) return;
  __shared__ float warr[128];
  int k = blockIdx.y, bx = blockIdx.x, t = threadIdx.x;
  int l = t & 63, wv = t >> 6;
  int n0 = bx * 128;
  const ushort* __restrict__ XAH = (const ushort*)(ws + OFF_XAH);
  const ushort* __restrict__ XAL = (const ushort*)(ws + OFF_XAL);
  const ushort* __restrict__ LBH = (const ushort*)(ws + OFF_LBH) + (size_t)k * 16384;
  const ushort* __restrict__ LBL = (const ushort*)(ws + OFF_LBL) + (size_t)k * 16384;
  f32x16 acc[4] = {};
  size_t ng4 = (size_t)(4 * bx + wv) * 4;
  #pragma unroll
  for (int ec = 0; ec < 4; ++ec) {
    #pragma unroll
    for (int ks = 0; ks < 2; ++ks) {
      size_t aoff = (((ng4 + ec) * 2 + ks) * 64 + l) * 8;
      bf16x8 ah = *(const bf16x8*)&XAH[aoff];
      bf16x8 al = *(const bf16x8*)&XAL[aoff];
      #pragma unroll
      for (int dg = 0; dg < 4; ++dg) {
        size_t boff = ((((size_t)dg * 4 + ec) * 2 + ks) * 64 + l) * 8;
        bf16x8 bh = *(const bf16x8*)&LBH[boff];
        bf16x8 bl = *(const bf16x8*)&LBL[boff];
        acc[dg] = __builtin_amdgcn_mfma_f32_32x32x16_bf16(ah, bh, acc[dg], 0, 0, 0);
        acc[dg] = __builtin_amdgcn_mfma_f32_32x32x16_bf16(ah, bl, acc[dg], 0, 0, 0);
        acc[dg] = __builtin_amdgcn_mfma_f32_32x32x16_bf16(al, bh, acc[dg], 0, 0, 0);
      }
    }
  }
  float tv[4];
  #pragma unroll
  for (int c = 0; c < 4; ++c) tv[c] = ws[OFF_T + k * DD + 32 * c + (l & 31)];
  float part[16];
  #pragma unroll
  for (int r = 0; r < 16; ++r) {
    float s = 0.f;
    #pragma unroll
    for (int c = 0; c < 4; ++c) { float d = acc[c][r] - tv[c]; s += d * d; }
    part[r] = s;
  }
  #pragma unroll
  for (int mk2 = 1; mk2 < 32; mk2 <<= 1)
    #pragma unroll
    for (int r = 0; r < 16; ++r) part[r] += __shfl_xor(part[r], mk2, 64);
  int h = l >> 5;
  if ((l & 31) < 16) {
    int r = l & 31;
    int row = (r & 3) + 8 * (r >> 2) + 4 * h + 32 * wv;   // verified C/D layout
    ws[OFF_W + k * NS + n0 + row] = part[r];
    if (final_pass) warr[row] = part[r];
  }
  if (final_pass) {
    __syncthreads();
    if (t < 64) {
      float s = warr[t] + warr[t + 64];
      #pragma unroll
      for (int mk2 = 1; mk2 < 64; mk2 <<= 1) s += __shfl_xor(s, mk2, 64);
      if (t == 0) atomicAdd(&ws[OFF_LOSSK + k], 0.5f * wts[k] * s);
    }
  }
}

// S_k += (w.X)^T X over NCHUNK samples; operands from frag-order XB arrays;
// A re-split with w on the fly. Fused num/sw: z = w*x is already computed in
// the repack, so per-thread sums + lane-pair shfl + one atomic per d replace
// k_quad's old gather epilogue.
__global__ __launch_bounds__(256) void k_scatter(float* __restrict__ ws, int guarded) {
  if (guarded && ((const int*)ws)[OFF_DONE]) return;
  int k = blockIdx.y, chunk = blockIdx.x, t = threadIdx.x;
  int l = t & 63, dg = t >> 6;
  const ushort* __restrict__ XBH = (const ushort*)(ws + OFF_XBH);
  const ushort* __restrict__ XBL = (const ushort*)(ws + OFF_XBL);
  const float* __restrict__ wp = ws + OFF_W + k * NS + chunk * NCHUNK;
  f32x16 acc[4] = {};
  int nb0 = chunk * (NCHUNK / 16);
  int ko = (l >> 5) * 8;
  float zsum = 0.f, wsum = 0.f;
  for (int st = 0; st < NCHUNK / 16; ++st) {
    size_t aoff = (((size_t)dg * (NS / 16) + nb0 + st) * 64 + l) * 8;
    bf16x8 th = *(const bf16x8*)&XBH[aoff];
    bf16x8 tl = *(const bf16x8*)&XBL[aoff];
    float4 w0 = *(const float4*)&wp[16 * st + ko];
    float4 w1 = *(const float4*)&wp[16 * st + ko + 4];
    float wj[8] = {w0.x, w0.y, w0.z, w0.w, w1.x, w1.y, w1.z, w1.w};
    bf16x8 ah, al;
    #pragma unroll
    for (int j = 0; j < 8; ++j) {
      float xf = bf2f((ushort)th[j]) + bf2f((ushort)tl[j]);
      float zf = wj[j] * xf;
      zsum += zf;                              // num[d] partial
      union { float f; unsigned u; } cz; cz.f = zf;
      ah[j] = (short)(ushort)(cz.u >> 16);
      union { unsigned u; float f; } ch; ch.u = cz.u & 0xffff0000u;
      al[j] = (short)f2bf_rne(zf - ch.f);
    }
    if (dg == 0 && (l & 31) == 0) {            // sw partial: 2 lanes cover all n
      #pragma unroll
      for (int j = 0; j < 8; ++j) wsum += wj[j];
    }
    #pragma unroll
    for (int eg = 0; eg < 4; ++eg) {
      size_t boff = (((size_t)eg * (NS / 16) + nb0 + st) * 64 + l) * 8;
      bf16x8 bh = *(const bf16x8*)&XBH[boff];
      bf16x8 bl = *(const bf16x8*)&XBL[boff];
      acc[eg] = __builtin_amdgcn_mfma_f32_32x32x16_bf16(ah, bh, acc[eg], 0, 0, 0);
      acc[eg] = __builtin_amdgcn_mfma_f32_32x32x16_bf16(ah, bl, acc[eg], 0, 0, 0);
      acc[eg] = __builtin_amdgcn_mfma_f32_32x32x16_bf16(al, bh, acc[eg], 0, 0, 0);
    }
  }
  // num/sw epilogue: combine lane pairs (l ^ 32 shares the same d)
  zsum += __shfl_xor(zsum, 32, 64);
  if (l < 32) atomicAdd(&ws[OFF_NUM + k * DD + 32 * dg + l], zsum);
  wsum += __shfl_xor(wsum, 32, 64);
  if (t == 0) atomicAdd(&ws[OFF_SW + k], wsum);
  // S epilogue
  float* __restrict__ S = ws + OFF_CS + (size_t)k * DD * DD;
  int h = l >> 5;
  #pragma unroll
  for (int eg = 0; eg < 4; ++eg) {
    int e = 32 * eg + (l & 31);
    #pragma unroll
    for (int r = 0; r < 16; ++r) {
      int drow = 32 * dg + (r & 3) + 8 * (r >> 2) + 4 * h;
      atomicAdd(&S[drow * DD + e], acc[eg][r]);
    }
  }
}

__global__ void k_lossfin(const float* __restrict__ weights, const float* __restrict__ ws,
                          float* __restrict__ dout) {
  if (threadIdx.x == 0 && blockIdx.x == 0) {
    float base = 0.f;
    for (int k = 0; k < KC; ++k)
      base += weights[k] * 0.5f * (float)NS * ((float)DD * LOG_2PI_ + ws[OFF_LOGDET + k])
            + ws[OFF_LOSSK + k];
    dout[0] = base;
  }
}

extern "C" void kernel_launch(void* const* d_in, const int* in_sizes, int n_in,
                              void* d_out, int out_size, void* d_ws, size_t ws_size,
                              hipStream_t stream) {
  const float* x       = (const float*)d_in[0];
  const float* means   = (const float*)d_in[1];
  const float* covs    = (const float*)d_in[2];
  const float* weights = (const float*)d_in[3];
  float* out = (float*)d_out;
  float* ws  = (float*)d_ws;

  hipLaunchKernelGGL(k_init_split, dim3(NS / 64), dim3(256), 0, stream, x, means, covs, ws);
  // first factorization of the initial covariances (no update phase)
  hipLaunchKernelGGL(k_fused, dim3(16), dim3(256), 0, stream, ws, out, 0, 0, 0, 0, 0);

  // 8 guarded EM iterations: w accumulation, then fused update+chol+trinv
  for (int u = 0; u < 8; ++u) {
    hipLaunchKernelGGL(k_quad,    dim3(128, 16), dim3(256), 0, stream, ws, weights, 1, 0);
    hipLaunchKernelGGL(k_scatter, dim3(NS / NCHUNK, 16), dim3(256), 0, stream, ws, 1);
    hipLaunchKernelGGL(k_fused,   dim3(16), dim3(256), 0, stream, ws, out, 1, 1, 0, 1, 0);
  }

  // final (always-executed) update + chol/trinv of c_fin, then loss
  hipLaunchKernelGGL(k_quad,    dim3(128, 16), dim3(256), 0, stream, ws, weights, 0, 0);
  hipLaunchKernelGGL(k_scatter, dim3(NS / NCHUNK, 16), dim3(256), 0, stream, ws, 0);
  hipLaunchKernelGGL(k_fused,   dim3(16), dim3(256), 0, stream, ws, out, 0, 1, 1, 0, 1);
  hipLaunchKernelGGL(k_quad,    dim3(128, 16), dim3(256), 0, stream, ws, weights, 0, 1);
  hipLaunchKernelGGL(k_lossfin, dim3(1), dim3(64), 0, stream, weights, ws, out);
}

// Round 12
// 1196.904 us; speedup vs baseline: 1.3819x; 1.0548x over previous
//
#include <hip/hip_runtime.h>
#include <math.h>

// GaussianMixtureLayer: EM loop (<=8 iters, device-side convergence flag) +
// final update + Gaussian log-prob loss. Heavy GEMMs on bf16 MFMA (hi/lo
// 3-term split), operands in FRAGMENT ORDER (wave-contiguous dwordx4 loads).
//   k_quad   : Y = X Linv^T, w = ||y - t||^2; also zeroes CS for the
//              upcoming scatter (2048 blocks do it for free; doing it in
//              16-block k_fused cost 1MB at 34GB/s latency-bound rates)
//   k_scatter: S_k = (w.X)^T X + fused num/sw. NCHUNK=512 (2 blocks/CU)
//   k_fused  : update + Cholesky + two-level trinv in one kernel; C and L
//              never leave LDS. Phase A is a coalesced float4 sweep with
//              cm/nm in LDS; LB writes are ushort4-vectorized. (round-11
//              k_fused was 121us = 4.2MB at 34GB/s — strided/2B accesses)

#define NS 16384
#define DD 128
#define KC 16
#define JITTER_ 1e-6f
#define EPS2_ 1e-6f            // (1e-3)^2 Frobenius convergence check
#define LOG_2PI_ 1.8378770664093454f
#define NCHUNK 512             // scatter samples per block

typedef __attribute__((ext_vector_type(8))) short bf16x8;
typedef __attribute__((ext_vector_type(16))) float f32x16;

// workspace float offsets
enum : int {
  OFF_CUR_M  = 0,            // 16*128
  OFF_CS     = 2048,         // 16*128*128  S accumulator (zeroed by k_quad)
  OFF_T      = 528384,       // t_k = Linv_k m_k (fp32)
  OFF_LOGDET = 530432,
  OFF_SW     = 530448,
  OFF_NUM    = 530464,       // 16*128
  OFF_W      = 532512,       // w[k][n]
  OFF_LOSSK  = 794656,       // 16 per-k loss partials
  OFF_DIFFSQ = 794672,
  OFF_DONE   = 794673,       // int
  OFF_CTR    = 794674,       // int, monotonic (no in-kernel reset)
  // frag-order bf16 arrays (ushort), 2 floats per 4 ushorts:
  OFF_XAH    = 794676,       // X row-side frags: [ng(512)][ec(4)][ks(2)][l(64)][8]
  OFF_XAL    = 1843252,
  OFF_XBH    = 2891828,      // X^T frags: [eg(4)][nb(1024)][l(64)][8]
  OFF_XBL    = 3940404,
  OFF_LBH    = 4988980,      // Linv frags per k: [k][dg(4)][ec(4)][ks(2)][l(64)][8]
  OFF_LBL    = 5120052,
  WS_FLOATS  = 5251124       // ~21 MB
};

__device__ __forceinline__ float bf2f(ushort u) {
  union { unsigned u; float f; } c; c.u = ((unsigned)u) << 16; return c.f;
}
__device__ __forceinline__ ushort f2bf_rne(float f) {
  union { float f; unsigned u; } c; c.f = f;
  unsigned r = c.u + 0x7fffu + ((c.u >> 16) & 1u);
  return (ushort)(r >> 16);
}
__device__ __forceinline__ ushort f2bf_trunc(float f) {
  union { float f; unsigned u; } c; c.f = f; return (ushort)(c.u >> 16);
}

// XOR-quad swizzle for 128x128 LDS matrix.
__device__ __forceinline__ int swz(int r, int c) {
  return (r << 7) + ((((c >> 2) + r) & 31) << 2) + (c & 3);
}

// init state + one-time bf16 hi/lo split of X into frag-order XA (row side)
// and XB (transposed side). Block b handles samples 64b..64b+63.
__global__ __launch_bounds__(256) void k_init_split(const float* __restrict__ x,
                                                    const float* __restrict__ means,
                                                    const float* __restrict__ covs,
                                                    float* __restrict__ ws) {
  __shared__ float xt[64 * 132];
  int b = blockIdx.x, t = threadIdx.x;
  int idx = b * 256 + t;
  for (int i = idx; i < KC * DD * DD; i += 256 * 256) ws[OFF_CS + i] = covs[i];
  if (idx < KC * DD) ws[OFF_CUR_M + idx] = means[idx];
  if (idx == 0) {
    ws[OFF_DIFFSQ] = 0.f;
    ((int*)ws)[OFF_DONE] = 0;
    ((int*)ws)[OFF_CTR]  = 0;
  }
  int n0 = b * 64;
  for (int fi = t; fi < 2048; fi += 256) {
    int n = fi >> 5, q = (fi & 31) * 4;
    *(float4*)&xt[n * 132 + q] = *(const float4*)&x[(size_t)(n0 + n) * DD + q];
  }
  __syncthreads();
  ushort* __restrict__ XAH = (ushort*)(ws + OFF_XAH);
  ushort* __restrict__ XAL = (ushort*)(ws + OFF_XAL);
  ushort* __restrict__ XBH = (ushort*)(ws + OFF_XBH);
  ushort* __restrict__ XBL = (ushort*)(ws + OFF_XBL);
  // XA: n = 32*ng+(l&31), e = 32ec+16ks+8(l>>5)+j
  for (int s = t; s < 1024; s += 256) {
    int l = s & 63, ks = (s >> 6) & 1, ec = (s >> 7) & 3, ngl = (s >> 9) & 1;
    int nl = 32 * ngl + (l & 31);
    int e0 = 32 * ec + 16 * ks + 8 * (l >> 5);
    float vv[8];
    *(float4*)&vv[0] = *(const float4*)&xt[nl * 132 + e0];
    *(float4*)&vv[4] = *(const float4*)&xt[nl * 132 + e0 + 4];
    ushort h[8], lo[8];
    #pragma unroll
    for (int j = 0; j < 8; ++j) {
      h[j]  = f2bf_trunc(vv[j]);
      lo[j] = f2bf_rne(vv[j] - bf2f(h[j]));
    }
    size_t base = ((((size_t)((n0 >> 5) + ngl) * 4 + ec) * 2 + ks) * 64 + l) * 8;
    *(ushort4*)&XAH[base]     = make_ushort4(h[0], h[1], h[2], h[3]);
    *(ushort4*)&XAH[base + 4] = make_ushort4(h[4], h[5], h[6], h[7]);
    *(ushort4*)&XAL[base]     = make_ushort4(lo[0], lo[1], lo[2], lo[3]);
    *(ushort4*)&XAL[base + 4] = make_ushort4(lo[4], lo[5], lo[6], lo[7]);
  }
  // XB: e = 32eg+(l&31), n = 16*nb+8(l>>5)+j
  for (int s = t; s < 1024; s += 256) {
    int l = s & 63, nbl = (s >> 6) & 3, eg = (s >> 8) & 3;
    int e = 32 * eg + (l & 31);
    int nl = 16 * nbl + 8 * (l >> 5);
    ushort h[8], lo[8];
    #pragma unroll
    for (int j = 0; j < 8; ++j) {
      float v = xt[(nl + j) * 132 + e];
      h[j]  = f2bf_trunc(v);
      lo[j] = f2bf_rne(v - bf2f(h[j]));
    }
    size_t base = (((size_t)eg * (NS / 16) + (n0 >> 4) + nbl) * 64 + l) * 8;
    *(ushort4*)&XBH[base]     = make_ushort4(h[0], h[1], h[2], h[3]);
    *(ushort4*)&XBH[base + 4] = make_ushort4(h[4], h[5], h[6], h[7]);
    *(ushort4*)&XBL[base]     = make_ushort4(lo[0], lo[1], lo[2], lo[3]);
    *(ushort4*)&XBL[base + 4] = make_ushort4(lo[4], lo[5], lo[6], lo[7]);
  }
}

// Fused update + Cholesky + triangular inverse. One block per component.
__global__ __launch_bounds__(256) void k_fused(float* __restrict__ ws, float* __restrict__ dout,
                                               int guarded, int do_update, int write_out,
                                               int accum_diff, int final_pass) {
  if (guarded && ((const int*)ws)[OFF_DONE]) return;
  __shared__ float m[DD * DD];      // 64 KB, swizzled: C then L
  __shared__ float Zs[DD * 132];    // 66 KB: Linv row-major
  __shared__ float Ws[64 * 68];     // 17 KB: GEMM1 temp
  __shared__ float invd_s[DD];
  __shared__ float cm_s[DD], nm_s[DD];
  __shared__ float redbuf[2];
  int k = blockIdx.x, t = threadIdx.x;
  int l = t & 63, wv = t >> 6;
  float* __restrict__ CS = ws + OFF_CS + (size_t)k * DD * DD;

  // ---------- phase A: build C in LDS (coalesced float4 sweep) ----------
  if (do_update) {
    float sw = ws[OFF_SW + k];
    float inv = 1.f / sw;
    if (t < DD) {
      cm_s[t] = ws[OFF_CUR_M + k * DD + t];
      nm_s[t] = ws[OFF_NUM + k * DD + t];
    }
    __syncthreads();
    float* __restrict__ doutC = dout + 1 + KC * DD + (size_t)k * DD * DD;
    #pragma unroll
    for (int it = 0; it < 16; ++it) {
      int idx = (it * 256 + t) * 4;
      float4 s4 = *(const float4*)&CS[idx];
      int d = idx >> 7, e = idx & 127;
      float md = cm_s[d], nd = nm_s[d];
      float4 me4 = *(const float4*)&cm_s[e];
      float4 ne4 = *(const float4*)&nm_s[e];
      float4 v;
      v.x = (s4.x - md * ne4.x - nd * me4.x + sw * md * me4.x) * inv;
      v.y = (s4.y - md * ne4.y - nd * me4.y + sw * md * me4.y) * inv;
      v.z = (s4.z - md * ne4.z - nd * me4.z + sw * md * me4.z) * inv;
      v.w = (s4.w - md * ne4.w - nd * me4.w + sw * md * me4.w) * inv;
      if (d >= e && d < e + 4) (&v.x)[d - e] += JITTER_;
      *(float4*)&m[swz(d, e)] = v;
      if (write_out) *(float4*)&doutC[idx] = v;
    }
    if (t < DD) {
      float me = cm_s[t], ne = nm_s[t];
      float newm = ne * inv;
      ws[OFF_CUR_M + k * DD + t] = newm;
      if (write_out) dout[1 + k * DD + t] = newm;
      if (accum_diff) {
        float dm = newm - me;
        float s = dm * dm;
        #pragma unroll
        for (int mk2 = 1; mk2 < 64; mk2 <<= 1) s += __shfl_xor(s, mk2, 64);
        if (l == 0) redbuf[wv] = s;
      }
      ws[OFF_NUM + k * DD + t] = 0.f;
    }
    if (t == 0) {
      ws[OFF_SW + k] = 0.f;
      if (final_pass) ws[OFF_LOSSK + k] = 0.f;
    }
    __syncthreads();
    if (accum_diff && t == 0) {
      atomicAdd(&ws[OFF_DIFFSQ], redbuf[0] + redbuf[1]);
      __threadfence();
      int old = atomicAdd((int*)ws + OFF_CTR, 1);
      if ((old & (KC - 1)) == KC - 1) {
        float v = atomicAdd(&ws[OFF_DIFFSQ], 0.f);
        if (v <= EPS2_) atomicExch((int*)ws + OFF_DONE, 1);
        atomicExch(&ws[OFF_DIFFSQ], 0.f);
      }
    }
  } else {
    #pragma unroll
    for (int it = 0; it < 16; ++it) {
      int idx = (it * 256 + t) * 4;
      float4 c4 = *(const float4*)&CS[idx];
      *(float4*)&m[swz(idx >> 7, idx & 127)] = c4;
    }
    if (t < DD) ws[OFF_NUM + k * DD + t] = 0.f;
    if (t == 0) ws[OFF_SW + k] = 0.f;
  }
  __syncthreads();

  // ---------- phase B: Cholesky, PANEL=16 wave-sync ----------
  for (int P = 0; P < DD; P += 16) {
    if (wv == 0) {
      int ra = P + l, rb = P + 64 + l;
      bool va = ra < DD, vb = rb < DD;
      float A[16], B[16];
      if (va) {
        #pragma unroll
        for (int q = 0; q < 4; ++q) {
          float4 v = *(const float4*)&m[swz(ra, P + 4 * q)];
          A[4*q+0] = v.x; A[4*q+1] = v.y; A[4*q+2] = v.z; A[4*q+3] = v.w;
        }
      }
      if (vb) {
        #pragma unroll
        for (int q = 0; q < 4; ++q) {
          float4 v = *(const float4*)&m[swz(rb, P + 4 * q)];
          B[4*q+0] = v.x; B[4*q+1] = v.y; B[4*q+2] = v.z; B[4*q+3] = v.w;
        }
      }
      #pragma unroll
      for (int jj = 0; jj < 16; ++jj) {
        float dj = __shfl(A[jj], jj, 64);
        float sj = sqrtf(dj);
        float inv = 1.f / sj;
        if (va) {
          if (l == jj) A[jj] = sj;
          else if (l > jj) A[jj] *= inv;
        }
        if (vb) B[jj] *= inv;
        #pragma unroll
        for (int jj2 = jj + 1; jj2 < 16; ++jj2) {
          float c = __shfl(A[jj], jj2, 64);
          if (va && l > jj) A[jj2] -= A[jj] * c;
          if (vb) B[jj2] -= B[jj] * c;
        }
      }
      if (va) {
        #pragma unroll
        for (int q = 0; q < 4; ++q)
          *(float4*)&m[swz(ra, P + 4 * q)] = make_float4(A[4*q], A[4*q+1], A[4*q+2], A[4*q+3]);
      }
      if (vb) {
        #pragma unroll
        for (int q = 0; q < 4; ++q)
          *(float4*)&m[swz(rb, P + 4 * q)] = make_float4(B[4*q], B[4*q+1], B[4*q+2], B[4*q+3]);
      }
    }
    __syncthreads();
    int R0 = P + 16;
    if (R0 < DD) {
      int s = DD - R0;
      int tq = R0 + (t & 31);
      for (int b = 0; b < s; b += 32) {
        int q = tq + b;
        if (q < DD) {
          float lq[16];
          #pragma unroll
          for (int p4 = 0; p4 < 4; ++p4) {
            float4 v = *(const float4*)&m[swz(q, P + 4 * p4)];
            lq[4*p4+0] = v.x; lq[4*p4+1] = v.y; lq[4*p4+2] = v.z; lq[4*p4+3] = v.w;
          }
          for (int i = R0 + (t >> 5); i < DD; i += 8) {
            float a = m[swz(i, q)];
            #pragma unroll
            for (int p4 = 0; p4 < 4; ++p4) {
              float4 v = *(const float4*)&m[swz(i, P + 4 * p4)];
              a -= v.x * lq[4*p4+0] + v.y * lq[4*p4+1] + v.z * lq[4*p4+2] + v.w * lq[4*p4+3];
            }
            m[swz(i, q)] = a;
          }
        }
      }
    }
    __syncthreads();
  }

  if (t < DD) invd_s[t] = 1.f / m[swz(t, t)];
  if (final_pass && t == 0) {
    float ld = 0.f;
    for (int i = 0; i < DD; ++i) ld += logf(m[swz(i, i)]);
    ws[OFF_LOGDET + k] = 2.f * ld;
  }
  __syncthreads();

  // ---------- phase C: two-level trinv (L read from LDS m) ----------
  if (t < 128) {
    int h = t >> 6, j = t & 63;
    float acc[64];
    #pragma unroll
    for (int i = 0; i < 64; ++i) acc[i] = 0.f;
    #pragma unroll
    for (int p = 0; p < 64; ++p) {
      float zp = (((p == j) ? 1.f : 0.f) - acc[p]) * invd_s[h * 64 + p];
      Zs[(h * 64 + p) * 132 + h * 64 + j] = zp;
      #pragma unroll
      for (int i = p + 1; i < 64; ++i)
        acc[i] += m[swz(h * 64 + i, h * 64 + p)] * zp;
    }
  } else {
    for (int s = t - 128; s < 4096; s += 128)
      Zs[(s >> 6) * 132 + 64 + (s & 63)] = 0.f;
  }
  __syncthreads();
  int i0 = (t & 15) * 4, j0 = (t >> 4) * 4;
  {  // GEMM1: W = C * Ainv
    float acc4[4][4] = {};
    for (int q = 0; q < 64; ++q) {
      float av[4];
      #pragma unroll
      for (int r = 0; r < 4; ++r) av[r] = m[swz(64 + i0 + r, q)];
      float4 b = *(const float4*)&Zs[q * 132 + j0];
      float bv[4] = {b.x, b.y, b.z, b.w};
      #pragma unroll
      for (int r = 0; r < 4; ++r)
        #pragma unroll
        for (int c = 0; c < 4; ++c) acc4[r][c] += av[r] * bv[c];
    }
    #pragma unroll
    for (int r = 0; r < 4; ++r)
      #pragma unroll
      for (int c = 0; c < 4; ++c) Ws[(i0 + r) * 68 + j0 + c] = acc4[r][c];
  }
  __syncthreads();
  {  // GEMM2: Linv21 = -Binv * W
    float acc4[4][4] = {};
    for (int q0 = 0; q0 < 64; q0 += 4) {
      float4 bi[4], wq[4];
      #pragma unroll
      for (int r = 0; r < 4; ++r)
        bi[r] = *(const float4*)&Zs[(64 + i0 + r) * 132 + 64 + q0];
      #pragma unroll
      for (int s = 0; s < 4; ++s)
        wq[s] = *(const float4*)&Ws[(q0 + s) * 68 + j0];
      #pragma unroll
      for (int r = 0; r < 4; ++r) {
        float br[4] = {bi[r].x, bi[r].y, bi[r].z, bi[r].w};
        #pragma unroll
        for (int s = 0; s < 4; ++s) {
          float wv2[4] = {wq[s].x, wq[s].y, wq[s].z, wq[s].w};
          #pragma unroll
          for (int c = 0; c < 4; ++c) acc4[r][c] += br[s] * wv2[c];
        }
      }
    }
    #pragma unroll
    for (int r = 0; r < 4; ++r)
      #pragma unroll
      for (int c = 0; c < 4; ++c) Zs[(64 + i0 + r) * 132 + j0 + c] = -acc4[r][c];
  }
  __syncthreads();
  if (t < 128) {   // t = Linv * m  (NEW means)
    const float* __restrict__ mk = ws + OFF_CUR_M + k * DD;
    float s0 = 0.f;
    for (int e = 0; e < DD; e += 4) {
      float4 z = *(const float4*)&Zs[t * 132 + e];
      s0 += z.x * mk[e] + z.y * mk[e + 1] + z.z * mk[e + 2] + z.w * mk[e + 3];
    }
    ws[OFF_T + k * DD + t] = s0;
  }
  // frag-order bf16 writes, one 8-elem frag per group -> ushort4 stores
  ushort* __restrict__ LBH = (ushort*)(ws + OFF_LBH) + (size_t)k * 16384;
  ushort* __restrict__ LBL = (ushort*)(ws + OFF_LBL) + (size_t)k * 16384;
  for (int g = t; g < 2048; g += 256) {
    int ll = g & 63, ks2 = (g >> 6) & 1, ec = (g >> 7) & 3, dg = (g >> 9) & 3;
    int d = 32 * dg + (ll & 31);
    int e = 32 * ec + 16 * ks2 + 8 * (ll >> 5);
    float4 z0 = *(const float4*)&Zs[d * 132 + e];
    float4 z1 = *(const float4*)&Zs[d * 132 + e + 4];
    float zv[8] = {z0.x, z0.y, z0.z, z0.w, z1.x, z1.y, z1.z, z1.w};
    ushort hh[8], lo2[8];
    #pragma unroll
    for (int j = 0; j < 8; ++j) {
      hh[j]  = f2bf_trunc(zv[j]);
      lo2[j] = f2bf_rne(zv[j] - bf2f(hh[j]));
    }
    *(ushort4*)&LBH[g * 8]     = make_ushort4(hh[0], hh[1], hh[2], hh[3]);
    *(ushort4*)&LBH[g * 8 + 4] = make_ushort4(hh[4], hh[5], hh[6], hh[7]);
    *(ushort4*)&LBL[g * 8]     = make_ushort4(lo2[0], lo2[1], lo2[2], lo2[3]);
    *(ushort4*)&LBL[g * 8 + 4] = make_ushort4(lo2[4], lo2[5], lo2[6], lo2[7]);
  }
}

// w[n,k] = ||X Linv^T - t||^2. Block: 128 samples x full 128 d, 4 waves.
// Also zeroes this block's slice of CS for the upcoming k_scatter.
__global__ __launch_bounds__(256) void k_quad(float* __restrict__ ws,
                                              const float* __restrict__ wts,
                                              int guarded, int final_pass) {
  if (guarded && ((const int*)ws)[OFF_DONE]) return;
  __shared__ float warr[128];
  int k = blockIdx.y, bx = blockIdx.x, t = threadIdx.x;
  int l = t & 63, wv = t >> 6;
  int n0 = bx * 128;
  if (t < 128) ws[OFF_CS + (size_t)k * DD * DD + bx * 128 + t] = 0.f;
  const ushort* __restrict__ XAH = (const ushort*)(ws + OFF_XAH);
  const ushort* __restrict__ XAL = (const ushort*)(ws + OFF_XAL);
  const ushort* __restrict__ LBH = (const ushort*)(ws + OFF_LBH) + (size_t)k * 16384;
  const ushort* __restrict__ LBL = (const ushort*)(ws + OFF_LBL) + (size_t)k * 16384;
  f32x16 acc[4] = {};
  size_t ng4 = (size_t)(4 * bx + wv) * 4;
  #pragma unroll
  for (int ec = 0; ec < 4; ++ec) {
    #pragma unroll
    for (int ks = 0; ks < 2; ++ks) {
      size_t aoff = (((ng4 + ec) * 2 + ks) * 64 + l) * 8;
      bf16x8 ah = *(const bf16x8*)&XAH[aoff];
      bf16x8 al = *(const bf16x8*)&XAL[aoff];
      #pragma unroll
      for (int dg = 0; dg < 4; ++dg) {
        size_t boff = ((((size_t)dg * 4 + ec) * 2 + ks) * 64 + l) * 8;
        bf16x8 bh = *(const bf16x8*)&LBH[boff];
        bf16x8 bl = *(const bf16x8*)&LBL[boff];
        acc[dg] = __builtin_amdgcn_mfma_f32_32x32x16_bf16(ah, bh, acc[dg], 0, 0, 0);
        acc[dg] = __builtin_amdgcn_mfma_f32_32x32x16_bf16(ah, bl, acc[dg], 0, 0, 0);
        acc[dg] = __builtin_amdgcn_mfma_f32_32x32x16_bf16(al, bh, acc[dg], 0, 0, 0);
      }
    }
  }
  float tv[4];
  #pragma unroll
  for (int c = 0; c < 4; ++c) tv[c] = ws[OFF_T + k * DD + 32 * c + (l & 31)];
  float part[16];
  #pragma unroll
  for (int r = 0; r < 16; ++r) {
    float s = 0.f;
    #pragma unroll
    for (int c = 0; c < 4; ++c) { float d = acc[c][r] - tv[c]; s += d * d; }
    part[r] = s;
  }
  #pragma unroll
  for (int mk2 = 1; mk2 < 32; mk2 <<= 1)
    #pragma unroll
    for (int r = 0; r < 16; ++r) part[r] += __shfl_xor(part[r], mk2, 64);
  int h = l >> 5;
  if ((l & 31) < 16) {
    int r = l & 31;
    int row = (r & 3) + 8 * (r >> 2) + 4 * h + 32 * wv;   // verified C/D layout
    ws[OFF_W + k * NS + n0 + row] = part[r];
    if (final_pass) warr[row] = part[r];
  }
  if (final_pass) {
    __syncthreads();
    if (t < 64) {
      float s = warr[t] + warr[t + 64];
      #pragma unroll
      for (int mk2 = 1; mk2 < 64; mk2 <<= 1) s += __shfl_xor(s, mk2, 64);
      if (t == 0) atomicAdd(&ws[OFF_LOSSK + k], 0.5f * wts[k] * s);
    }
  }
}

// S_k += (w.X)^T X over NCHUNK samples; operands from frag-order XB arrays;
// A re-split with w on the fly. Fused num/sw accumulation.
__global__ __launch_bounds__(256) void k_scatter(float* __restrict__ ws, int guarded) {
  if (guarded && ((const int*)ws)[OFF_DONE]) return;
  int k = blockIdx.y, chunk = blockIdx.x, t = threadIdx.x;
  int l = t & 63, dg = t >> 6;
  const ushort* __restrict__ XBH = (const ushort*)(ws + OFF_XBH);
  const ushort* __restrict__ XBL = (const ushort*)(ws + OFF_XBL);
  const float* __restrict__ wp = ws + OFF_W + k * NS + chunk * NCHUNK;
  f32x16 acc[4] = {};
  int nb0 = chunk * (NCHUNK / 16);
  int ko = (l >> 5) * 8;
  float zsum = 0.f, wsum = 0.f;
  for (int st = 0; st < NCHUNK / 16; ++st) {
    size_t aoff = (((size_t)dg * (NS / 16) + nb0 + st) * 64 + l) * 8;
    bf16x8 th = *(const bf16x8*)&XBH[aoff];
    bf16x8 tl = *(const bf16x8*)&XBL[aoff];
    float4 w0 = *(const float4*)&wp[16 * st + ko];
    float4 w1 = *(const float4*)&wp[16 * st + ko + 4];
    float wj[8] = {w0.x, w0.y, w0.z, w0.w, w1.x, w1.y, w1.z, w1.w};
    bf16x8 ah, al;
    #pragma unroll
    for (int j = 0; j < 8; ++j) {
      float xf = bf2f((ushort)th[j]) + bf2f((ushort)tl[j]);
      float zf = wj[j] * xf;
      zsum += zf;                              // num[d] partial
      union { float f; unsigned u; } cz; cz.f = zf;
      ah[j] = (short)(ushort)(cz.u >> 16);
      union { unsigned u; float f; } ch; ch.u = cz.u & 0xffff0000u;
      al[j] = (short)f2bf_rne(zf - ch.f);
    }
    if (dg == 0 && (l & 31) == 0) {            // sw partial: 2 lanes cover all n
      #pragma unroll
      for (int j = 0; j < 8; ++j) wsum += wj[j];
    }
    #pragma unroll
    for (int eg = 0; eg < 4; ++eg) {
      size_t boff = (((size_t)eg * (NS / 16) + nb0 + st) * 64 + l) * 8;
      bf16x8 bh = *(const bf16x8*)&XBH[boff];
      bf16x8 bl = *(const bf16x8*)&XBL[boff];
      acc[eg] = __builtin_amdgcn_mfma_f32_32x32x16_bf16(ah, bh, acc[eg], 0, 0, 0);
      acc[eg] = __builtin_amdgcn_mfma_f32_32x32x16_bf16(ah, bl, acc[eg], 0, 0, 0);
      acc[eg] = __builtin_amdgcn_mfma_f32_32x32x16_bf16(al, bh, acc[eg], 0, 0, 0);
    }
  }
  // num/sw epilogue: combine lane pairs (l ^ 32 shares the same d)
  zsum += __shfl_xor(zsum, 32, 64);
  if (l < 32) atomicAdd(&ws[OFF_NUM + k * DD + 32 * dg + l], zsum);
  wsum += __shfl_xor(wsum, 32, 64);
  if (t == 0) atomicAdd(&ws[OFF_SW + k], wsum);
  // S epilogue
  float* __restrict__ S = ws + OFF_CS + (size_t)k * DD * DD;
  int h = l >> 5;
  #pragma unroll
  for (int eg = 0; eg < 4; ++eg) {
    int e = 32 * eg + (l & 31);
    #pragma unroll
    for (int r = 0; r < 16; ++r) {
      int drow = 32 * dg + (r & 3) + 8 * (r >> 2) + 4 * h;
      atomicAdd(&S[drow * DD + e], acc[eg][r]);
    }
  }
}

__global__ void k_lossfin(const float* __restrict__ weights, const float* __restrict__ ws,
                          float* __restrict__ dout) {
  if (threadIdx.x == 0 && blockIdx.x == 0) {
    float base = 0.f;
    for (int k = 0; k < KC; ++k)
      base += weights[k] * 0.5f * (float)NS * ((float)DD * LOG_2PI_ + ws[OFF_LOGDET + k])
            + ws[OFF_LOSSK + k];
    dout[0] = base;
  }
}

extern "C" void kernel_launch(void* const* d_in, const int* in_sizes, int n_in,
                              void* d_out, int out_size, void* d_ws, size_t ws_size,
                              hipStream_t stream) {
  const float* x       = (const float*)d_in[0];
  const float* means   = (const float*)d_in[1];
  const float* covs    = (const float*)d_in[2];
  const float* weights = (const float*)d_in[3];
  float* out = (float*)d_out;
  float* ws  = (float*)d_ws;

  hipLaunchKernelGGL(k_init_split, dim3(NS / 64), dim3(256), 0, stream, x, means, covs, ws);
  // first factorization of the initial covariances (no update phase)
  hipLaunchKernelGGL(k_fused, dim3(16), dim3(256), 0, stream, ws, out, 0, 0, 0, 0, 0);

  // 8 guarded EM iterations: w accumulation, then fused update+chol+trinv
  for (int u = 0; u < 8; ++u) {
    hipLaunchKernelGGL(k_quad,    dim3(128, 16), dim3(256), 0, stream, ws, weights, 1, 0);
    hipLaunchKernelGGL(k_scatter, dim3(NS / NCHUNK, 16), dim3(256), 0, stream, ws, 1);
    hipLaunchKernelGGL(k_fused,   dim3(16), dim3(256), 0, stream, ws, out, 1, 1, 0, 1, 0);
  }

  // final (always-executed) update + chol/trinv of c_fin, then loss
  hipLaunchKernelGGL(k_quad,    dim3(128, 16), dim3(256), 0, stream, ws, weights, 0, 0);
  hipLaunchKernelGGL(k_scatter, dim3(NS / NCHUNK, 16), dim3(256), 0, stream, ws, 0);
  hipLaunchKernelGGL(k_fused,   dim3(16), dim3(256), 0, stream, ws, out, 0, 1, 1, 0, 1);
  hipLaunchKernelGGL(k_quad,    dim3(128, 16), dim3(256), 0, stream, ws, weights, 0, 1);
  hipLaunchKernelGGL(k_lossfin, dim3(1), dim3(64), 0, stream, weights, ws, out);
}